// Round 2
// baseline (197.089 us; speedup 1.0000x reference)
//
#include <hip/hip_runtime.h>

#define N_NODES 100000
#define N_EDGES 640000
#define HIDDEN 128

// ---------------------------------------------------------------------------
// Layer-1 edge scatter, planar replicated accumulators.
// agg layout: [4 channels][R replicas][N nodes]  (planar: one edge's 4 atomics
// hit 4 distant sectors; replica r = e & (R-1) spreads same-node edges over R
// independent planes to cut same-address RMW serialization.)
// ---------------------------------------------------------------------------
template <int R>
__global__ void scatter1_kernel(const int* __restrict__ ei,
                                const float* __restrict__ ea,
                                const float* __restrict__ x,
                                float* __restrict__ agg) {
    int e = blockIdx.x * blockDim.x + threadIdx.x;
    if (e >= N_EDGES) return;
    int src = ei[e];
    int dst = ei[N_EDGES + e];
    float w = ea[e];
    float4 xv = reinterpret_cast<const float4*>(x)[src];
    int r = e & (R - 1);
    atomicAdd(&agg[(size_t)(0 * R + r) * N_NODES + dst], xv.x * w);
    atomicAdd(&agg[(size_t)(1 * R + r) * N_NODES + dst], xv.y * w);
    atomicAdd(&agg[(size_t)(2 * R + r) * N_NODES + dst], xv.z * w);
    atomicAdd(&agg[(size_t)(3 * R + r) * N_NODES + dst], xv.w * w);
}

// ---------------------------------------------------------------------------
// Per-node fused MLP; h never exists in global memory.
// Reads the R replica planes (coalesced), computes
//   h = relu(agg@W1_rel + b1 + x@W1_root);  s_rel = h@W2_rel;
//   out = h@W2_root + b2.
// ---------------------------------------------------------------------------
template <int R>
__global__ void node_kernel(const float* __restrict__ x,
                            const float* __restrict__ agg,
                            const float* __restrict__ W1_rel,
                            const float* __restrict__ b1,
                            const float* __restrict__ W1_root,
                            const float* __restrict__ W2_rel,
                            const float* __restrict__ b2,
                            const float* __restrict__ W2_root,
                            float* __restrict__ s_rel,
                            float* __restrict__ out) {
    __shared__ float sW1r[4 * HIDDEN];
    __shared__ float sW1o[4 * HIDDEN];
    __shared__ float sb1[HIDDEN];
    __shared__ float sW2r[HIDDEN];
    __shared__ float sW2o[HIDDEN];

    for (int i = threadIdx.x; i < 4 * HIDDEN; i += blockDim.x) {
        sW1r[i] = W1_rel[i];
        sW1o[i] = W1_root[i];
    }
    for (int i = threadIdx.x; i < HIDDEN; i += blockDim.x) {
        sb1[i]  = b1[i];
        sW2r[i] = W2_rel[i];
        sW2o[i] = W2_root[i];
    }
    __syncthreads();

    int n = blockIdx.x * blockDim.x + threadIdx.x;
    if (n >= N_NODES) return;

    float4 xv = reinterpret_cast<const float4*>(x)[n];

    float a0 = 0.f, a1 = 0.f, a2 = 0.f, a3 = 0.f;
#pragma unroll
    for (int r = 0; r < R; ++r) {
        a0 += agg[(size_t)(0 * R + r) * N_NODES + n];
        a1 += agg[(size_t)(1 * R + r) * N_NODES + n];
        a2 += agg[(size_t)(2 * R + r) * N_NODES + n];
        a3 += agg[(size_t)(3 * R + r) * N_NODES + n];
    }

    float srel = 0.f, sroot = 0.f;
#pragma unroll 4
    for (int j = 0; j < HIDDEN; ++j) {
        float pre = sb1[j]
                  + a0 * sW1r[0 * HIDDEN + j]
                  + a1 * sW1r[1 * HIDDEN + j]
                  + a2 * sW1r[2 * HIDDEN + j]
                  + a3 * sW1r[3 * HIDDEN + j]
                  + xv.x * sW1o[0 * HIDDEN + j]
                  + xv.y * sW1o[1 * HIDDEN + j]
                  + xv.z * sW1o[2 * HIDDEN + j]
                  + xv.w * sW1o[3 * HIDDEN + j];
        float h = fmaxf(pre, 0.f);
        srel  += h * sW2r[j];
        sroot += h * sW2o[j];
    }
    s_rel[n] = srel;
    out[n]   = sroot + b2[0];
}

// ---------------------------------------------------------------------------
// Layer-2 scalar scatter into R replica planes.
// ---------------------------------------------------------------------------
template <int R>
__global__ void scatter2_kernel(const int* __restrict__ ei,
                                const float* __restrict__ ea,
                                const float* __restrict__ s_rel,
                                float* __restrict__ s2) {
    int e = blockIdx.x * blockDim.x + threadIdx.x;
    if (e >= N_EDGES) return;
    int src = ei[e];
    int dst = ei[N_EDGES + e];
    int r = e & (R - 1);
    atomicAdd(&s2[(size_t)r * N_NODES + dst], s_rel[src] * ea[e]);
}

// out[n] += sum_r s2[r][n]
template <int R>
__global__ void finalize_kernel(const float* __restrict__ s2,
                                float* __restrict__ out) {
    int n = blockIdx.x * blockDim.x + threadIdx.x;
    if (n >= N_NODES) return;
    float s = 0.f;
#pragma unroll
    for (int r = 0; r < R; ++r) s += s2[(size_t)r * N_NODES + n];
    out[n] += s;
}

template <int R>
static void run_all(const float* x, const int* ei, const float* ea,
                    const float* W1_rel, const float* b1, const float* W1_root,
                    const float* W2_rel, const float* b2, const float* W2_root,
                    float* out, float* ws, hipStream_t stream) {
    // ws layout: agg [4*R*N] | s2 [R*N] | s_rel [N]
    float* agg   = ws;
    float* s2    = agg + (size_t)4 * R * N_NODES;
    float* s_rel = s2 + (size_t)R * N_NODES;

    hipMemsetAsync(ws, 0, (size_t)5 * R * N_NODES * sizeof(float), stream);

    dim3 blk(256);
    dim3 grdE((N_EDGES + 255) / 256);
    dim3 grdN((N_NODES + 255) / 256);

    scatter1_kernel<R><<<grdE, blk, 0, stream>>>(ei, ea, x, agg);
    node_kernel<R><<<grdN, blk, 0, stream>>>(x, agg, W1_rel, b1, W1_root,
                                             W2_rel, b2, W2_root, s_rel, out);
    scatter2_kernel<R><<<grdE, blk, 0, stream>>>(ei, ea, s_rel, s2);
    finalize_kernel<R><<<grdN, blk, 0, stream>>>(s2, out);
}

extern "C" void kernel_launch(void* const* d_in, const int* in_sizes, int n_in,
                              void* d_out, int out_size, void* d_ws, size_t ws_size,
                              hipStream_t stream) {
    const float* x       = (const float*)d_in[0];
    const int*   ei      = (const int*)  d_in[1];
    const float* ea      = (const float*)d_in[2];
    const float* W1_rel  = (const float*)d_in[3];
    const float* b1      = (const float*)d_in[4];
    const float* W1_root = (const float*)d_in[5];
    const float* W2_rel  = (const float*)d_in[6];
    const float* b2      = (const float*)d_in[7];
    const float* W2_root = (const float*)d_in[8];
    float* out = (float*)d_out;
    float* ws  = (float*)d_ws;

    auto need = [](int R) {
        return (size_t)(5 * R + 1) * N_NODES * sizeof(float);
    };

    if (ws_size >= need(8)) {
        run_all<8>(x, ei, ea, W1_rel, b1, W1_root, W2_rel, b2, W2_root, out, ws, stream);
    } else if (ws_size >= need(4)) {
        run_all<4>(x, ei, ea, W1_rel, b1, W1_root, W2_rel, b2, W2_root, out, ws, stream);
    } else if (ws_size >= need(2)) {
        run_all<2>(x, ei, ea, W1_rel, b1, W1_root, W2_rel, b2, W2_root, out, ws, stream);
    } else {
        run_all<1>(x, ei, ea, W1_rel, b1, W1_root, W2_rel, b2, W2_root, out, ws, stream);
    }
}

// Round 3
// 65.907 us; speedup vs baseline: 2.9904x; 2.9904x over previous
//
#include <hip/hip_runtime.h>

#define N_NODES 100000
#define N_EDGES 640000
#define HIDDEN 128

// Bucketed counting-sort parameters
#define NB   200      // nodes per bucket
#define NBKT 500      // buckets; NB*NBKT == N_NODES
#define PART_BLOCKS 125
#define EPT 20        // edges/thread in partition: 125 blocks * 256 thr * 20 == N_EDGES

// ---------------------------------------------------------------------------
// Partition: bin edges by dst bucket into fixed-capacity regions.
// Record: x = src | (dst_local << 17)   (src<2^17, dst_local<200<2^9), y = w bits.
// Global atomics: only ~62K int reserve-ops (vs 2.56M fp32 before).
// ---------------------------------------------------------------------------
template <int CAP>
__global__ __launch_bounds__(256) void partition_kernel(const int* __restrict__ ei,
                                                        const float* __restrict__ ea,
                                                        uint2* __restrict__ recs,
                                                        int* __restrict__ cursor) {
    __shared__ int hist[NBKT];
    __shared__ int base[NBKT];
    for (int i = threadIdx.x; i < NBKT; i += 256) hist[i] = 0;
    __syncthreads();

    const int e0 = blockIdx.x * (256 * EPT) + threadIdx.x;
#pragma unroll
    for (int k = 0; k < EPT; ++k) {
        int d = ei[N_EDGES + e0 + k * 256];
        atomicAdd(&hist[d / NB], 1);
    }
    __syncthreads();

    for (int i = threadIdx.x; i < NBKT; i += 256) {
        int h = hist[i];
        base[i] = h ? atomicAdd(&cursor[i], h) : 0;
    }
    __syncthreads();
    for (int i = threadIdx.x; i < NBKT; i += 256) hist[i] = 0;  // reuse as local cursor
    __syncthreads();

#pragma unroll
    for (int k = 0; k < EPT; ++k) {
        int e = e0 + k * 256;
        int s = ei[e];
        int d = ei[N_EDGES + e];
        float w = ea[e];
        int b  = d / NB;
        int dl = d - b * NB;
        int slot = base[b] + atomicAdd(&hist[b], 1);
        if (slot < CAP)
            recs[(size_t)b * CAP + slot] =
                make_uint2((unsigned)s | ((unsigned)dl << 17), __float_as_uint(w));
    }
}

// ---------------------------------------------------------------------------
// Layer-1 aggregation: one block per bucket, LDS accumulators, non-atomic
// coalesced global write (bucket exclusively owns nodes [b*NB, (b+1)*NB)).
// ---------------------------------------------------------------------------
template <int CAP>
__global__ __launch_bounds__(256) void agg1_kernel(const uint2* __restrict__ recs,
                                                   const int* __restrict__ cursor,
                                                   const float* __restrict__ x,
                                                   float* __restrict__ agg) {
    __shared__ float acc[NB * 4];
    for (int i = threadIdx.x; i < NB * 4; i += 256) acc[i] = 0.f;
    __syncthreads();

    const int b = blockIdx.x;
    const int cnt = min(cursor[b], CAP);
    const uint2* r = recs + (size_t)b * CAP;
    for (int i = threadIdx.x; i < cnt; i += 256) {
        uint2 rec = r[i];
        int src = rec.x & 0x1FFFF;
        int dl  = rec.x >> 17;
        float w = __uint_as_float(rec.y);
        float4 xv = reinterpret_cast<const float4*>(x)[src];
        atomicAdd(&acc[dl * 4 + 0], xv.x * w);
        atomicAdd(&acc[dl * 4 + 1], xv.y * w);
        atomicAdd(&acc[dl * 4 + 2], xv.z * w);
        atomicAdd(&acc[dl * 4 + 3], xv.w * w);
    }
    __syncthreads();

    for (int t = threadIdx.x; t < NB; t += 256) {
        float4 v = make_float4(acc[t * 4 + 0], acc[t * 4 + 1],
                               acc[t * 4 + 2], acc[t * 4 + 3]);
        reinterpret_cast<float4*>(agg)[b * NB + t] = v;
    }
}

// ---------------------------------------------------------------------------
// Per-node fused MLP; h lives only in registers.
//   out[n] = h@W2_root + b2 (layer-2 root term); s_rel feeds layer-2 scatter.
// ---------------------------------------------------------------------------
__global__ __launch_bounds__(256) void node_kernel(const float* __restrict__ x,
                            const float* __restrict__ agg,
                            const float* __restrict__ W1_rel,
                            const float* __restrict__ b1,
                            const float* __restrict__ W1_root,
                            const float* __restrict__ W2_rel,
                            const float* __restrict__ b2,
                            const float* __restrict__ W2_root,
                            float* __restrict__ s_rel,
                            float* __restrict__ out) {
    __shared__ float sW1r[4 * HIDDEN];
    __shared__ float sW1o[4 * HIDDEN];
    __shared__ float sb1[HIDDEN];
    __shared__ float sW2r[HIDDEN];
    __shared__ float sW2o[HIDDEN];

    for (int i = threadIdx.x; i < 4 * HIDDEN; i += blockDim.x) {
        sW1r[i] = W1_rel[i];
        sW1o[i] = W1_root[i];
    }
    for (int i = threadIdx.x; i < HIDDEN; i += blockDim.x) {
        sb1[i]  = b1[i];
        sW2r[i] = W2_rel[i];
        sW2o[i] = W2_root[i];
    }
    __syncthreads();

    int n = blockIdx.x * blockDim.x + threadIdx.x;
    if (n >= N_NODES) return;

    float4 xv = reinterpret_cast<const float4*>(x)[n];
    float4 av = reinterpret_cast<const float4*>(agg)[n];

    float srel = 0.f, sroot = 0.f;
#pragma unroll 4
    for (int j = 0; j < HIDDEN; ++j) {
        float pre = sb1[j]
                  + av.x * sW1r[0 * HIDDEN + j]
                  + av.y * sW1r[1 * HIDDEN + j]
                  + av.z * sW1r[2 * HIDDEN + j]
                  + av.w * sW1r[3 * HIDDEN + j]
                  + xv.x * sW1o[0 * HIDDEN + j]
                  + xv.y * sW1o[1 * HIDDEN + j]
                  + xv.z * sW1o[2 * HIDDEN + j]
                  + xv.w * sW1o[3 * HIDDEN + j];
        float h = fmaxf(pre, 0.f);
        srel  += h * sW2r[j];
        sroot += h * sW2o[j];
    }
    s_rel[n] = srel;
    out[n]   = sroot + b2[0];
}

// ---------------------------------------------------------------------------
// Layer-2 aggregation: scalar LDS accumulate, non-atomic out +=.
// ---------------------------------------------------------------------------
template <int CAP>
__global__ __launch_bounds__(256) void agg2_kernel(const uint2* __restrict__ recs,
                                                   const int* __restrict__ cursor,
                                                   const float* __restrict__ s_rel,
                                                   float* __restrict__ out) {
    __shared__ float acc[NB];
    for (int i = threadIdx.x; i < NB; i += 256) acc[i] = 0.f;
    __syncthreads();

    const int b = blockIdx.x;
    const int cnt = min(cursor[b], CAP);
    const uint2* r = recs + (size_t)b * CAP;
    for (int i = threadIdx.x; i < cnt; i += 256) {
        uint2 rec = r[i];
        int src = rec.x & 0x1FFFF;
        int dl  = rec.x >> 17;
        atomicAdd(&acc[dl], s_rel[src] * __uint_as_float(rec.y));
    }
    __syncthreads();

    for (int t = threadIdx.x; t < NB; t += 256)
        out[b * NB + t] += acc[t];
}

// ---------------------------------------------------------------------------
// Legacy fallback (ws too small): direct global-atomic path from round 0.
// ---------------------------------------------------------------------------
__global__ void scatter1_legacy(const int* __restrict__ ei, const float* __restrict__ ea,
                                const float* __restrict__ x, float* __restrict__ agg) {
    int e = blockIdx.x * blockDim.x + threadIdx.x;
    if (e >= N_EDGES) return;
    int src = ei[e], dst = ei[N_EDGES + e];
    float w = ea[e];
    float4 xv = reinterpret_cast<const float4*>(x)[src];
    atomicAdd(&agg[dst * 4 + 0], xv.x * w);
    atomicAdd(&agg[dst * 4 + 1], xv.y * w);
    atomicAdd(&agg[dst * 4 + 2], xv.z * w);
    atomicAdd(&agg[dst * 4 + 3], xv.w * w);
}

__global__ void scatter2_legacy(const int* __restrict__ ei, const float* __restrict__ ea,
                                const float* __restrict__ s_rel, float* __restrict__ out) {
    int e = blockIdx.x * blockDim.x + threadIdx.x;
    if (e >= N_EDGES) return;
    atomicAdd(&out[ei[N_EDGES + e]], s_rel[ei[e]] * ea[e]);
}

extern "C" void kernel_launch(void* const* d_in, const int* in_sizes, int n_in,
                              void* d_out, int out_size, void* d_ws, size_t ws_size,
                              hipStream_t stream) {
    const float* x       = (const float*)d_in[0];
    const int*   ei      = (const int*)  d_in[1];
    const float* ea      = (const float*)d_in[2];
    const float* W1_rel  = (const float*)d_in[3];
    const float* b1      = (const float*)d_in[4];
    const float* W1_root = (const float*)d_in[5];
    const float* W2_rel  = (const float*)d_in[6];
    const float* b2      = (const float*)d_in[7];
    const float* W2_root = (const float*)d_in[8];
    float* out = (float*)d_out;
    char*  ws  = (char*)d_ws;

    // ws layout: agg [N*4 f] | s_rel [N f] | cursor [512 ints] | recs [NBKT*CAP uint2]
    float* agg    = (float*)ws;
    float* s_rel  = agg + (size_t)N_NODES * 4;
    int*   cursor = (int*)(s_rel + N_NODES);
    uint2* recs   = (uint2*)((char*)cursor + 2048);
    const size_t head = (size_t)N_NODES * 4 * 4 + (size_t)N_NODES * 4 + 2048;

    dim3 blk(256);
    dim3 grdN((N_NODES + 255) / 256);

    auto run_bucketed = [&](auto cap_tag) {
        constexpr int CAP = decltype(cap_tag)::value;
        hipMemsetAsync(cursor, 0, 2048, stream);
        partition_kernel<CAP><<<PART_BLOCKS, blk, 0, stream>>>(ei, ea, recs, cursor);
        agg1_kernel<CAP><<<NBKT, blk, 0, stream>>>(recs, cursor, x, agg);
        node_kernel<<<grdN, blk, 0, stream>>>(x, agg, W1_rel, b1, W1_root,
                                              W2_rel, b2, W2_root, s_rel, out);
        agg2_kernel<CAP><<<NBKT, blk, 0, stream>>>(recs, cursor, s_rel, out);
    };

    if (ws_size >= head + (size_t)NBKT * 2048 * sizeof(uint2)) {
        run_bucketed(std::integral_constant<int, 2048>{});
    } else if (ws_size >= head + (size_t)NBKT * 1664 * sizeof(uint2)) {
        run_bucketed(std::integral_constant<int, 1664>{});
    } else {
        // Legacy global-atomic path
        dim3 grdE((N_EDGES + 255) / 256);
        hipMemsetAsync(agg, 0, (size_t)N_NODES * 4 * sizeof(float), stream);
        scatter1_legacy<<<grdE, blk, 0, stream>>>(ei, ea, x, agg);
        node_kernel<<<grdN, blk, 0, stream>>>(x, agg, W1_rel, b1, W1_root,
                                              W2_rel, b2, W2_root, s_rel, out);
        scatter2_legacy<<<grdE, blk, 0, stream>>>(ei, ea, s_rel, out);
    }
}

// Round 4
// 64.457 us; speedup vs baseline: 3.0577x; 1.0225x over previous
//
#include <hip/hip_runtime.h>

#define N_NODES 100000
#define N_EDGES 640000
#define HIDDEN 128

// Bucketed counting-sort parameters
#define NB   200              // nodes per bucket
#define NBKT 500              // buckets; NB*NBKT == N_NODES
#define PB   125              // partition blocks
#define PT   512              // partition threads
#define EPT  10               // edges/thread: PB*PT*EPT == N_EDGES
#define BLK_RECS (PT * EPT)   // 5120 records per partition block

// ---------------------------------------------------------------------------
// Zero the 500-entry global bucket cursor (replaces hipMemsetAsync node).
// ---------------------------------------------------------------------------
__global__ void zero_cursor(int* __restrict__ cursor) {
    if (threadIdx.x < NBKT) cursor[threadIdx.x] = 0;
}

// ---------------------------------------------------------------------------
// Partition with LDS sort: bin edges by dst bucket, sort the block's 5120
// records by bucket in LDS, then write bucket-contiguous runs to global
// (consecutive lanes -> consecutive addresses => coalesced, ~3.5x fewer
// write messages than the previous per-record scattered stores).
// Record: x = src | (dst_local << 17), y = w bits.
// ---------------------------------------------------------------------------
template <int CAP>
__global__ __launch_bounds__(PT) void partition_kernel(const int* __restrict__ ei,
                                                       const float* __restrict__ ea,
                                                       uint2* __restrict__ recs,
                                                       int* __restrict__ cursor) {
    __shared__ int   hist[NBKT];
    __shared__ int   start[NBKT + 1];
    __shared__ int   wcur[NBKT];
    __shared__ int   gbase[NBKT];
    __shared__ int   scan[PT];
    __shared__ uint2 srec[BLK_RECS];   // 40 KB

    const int tid = threadIdx.x;

    for (int i = tid; i < NBKT; i += PT) hist[i] = 0;
    __syncthreads();

    // Phase 1: load edges to registers, count per-bucket histogram.
    const int e0 = blockIdx.x * BLK_RECS + tid;
    int   dsts[EPT];
    int   srcs[EPT];
    float wts[EPT];
#pragma unroll
    for (int k = 0; k < EPT; ++k) {
        int e = e0 + k * PT;
        srcs[k] = ei[e];
        dsts[k] = ei[N_EDGES + e];
        wts[k]  = ea[e];
        atomicAdd(&hist[dsts[k] / NB], 1);
    }
    __syncthreads();

    // Phase 2: exclusive scan of hist (Hillis-Steele over PT=512 slots).
    int v = (tid < NBKT) ? hist[tid] : 0;
    scan[tid] = v;
    __syncthreads();
#pragma unroll
    for (int off = 1; off < PT; off <<= 1) {
        int t = (tid >= off) ? scan[tid - off] : 0;
        __syncthreads();
        scan[tid] += t;
        __syncthreads();
    }
    if (tid < NBKT) {
        start[tid] = scan[tid] - v;       // exclusive
        wcur[tid]  = scan[tid] - v;
        gbase[tid] = v ? atomicAdd(&cursor[tid], v) : 0;
    }
    if (tid == 0) start[NBKT] = BLK_RECS;
    __syncthreads();

    // Phase 3: scatter records into LDS in bucket-sorted order.
#pragma unroll
    for (int k = 0; k < EPT; ++k) {
        int d  = dsts[k];
        int b  = d / NB;
        int dl = d - b * NB;
        int slot = atomicAdd(&wcur[b], 1);
        srec[slot] = make_uint2((unsigned)srcs[k] | ((unsigned)dl << 17),
                                __float_as_uint(wts[k]));
    }
    __syncthreads();

    // Phase 4: stream sorted records to global; bucket via binary search on
    // start[] (9 LDS broadcast reads). Neighbor lanes share buckets =>
    // consecutive destination addresses => coalesced run writes.
    for (int j = tid; j < BLK_RECS; j += PT) {
        int lo = 0, hi = NBKT;            // start[lo] <= j < start[hi]
        while (hi - lo > 1) {
            int mid = (lo + hi) >> 1;
            if (start[mid] <= j) lo = mid; else hi = mid;
        }
        int off = gbase[lo] + (j - start[lo]);
        if (off < CAP)
            recs[(size_t)lo * CAP + off] = srec[j];
    }
}

// ---------------------------------------------------------------------------
// Layer-1 aggregation: one block per bucket, LDS accumulators, non-atomic
// coalesced global write (bucket exclusively owns nodes [b*NB, (b+1)*NB)).
// ---------------------------------------------------------------------------
template <int CAP>
__global__ __launch_bounds__(256) void agg1_kernel(const uint2* __restrict__ recs,
                                                   const int* __restrict__ cursor,
                                                   const float* __restrict__ x,
                                                   float* __restrict__ agg) {
    __shared__ float acc[NB * 4];
    for (int i = threadIdx.x; i < NB * 4; i += 256) acc[i] = 0.f;
    __syncthreads();

    const int b = blockIdx.x;
    const int cnt = min(cursor[b], CAP);
    const uint2* r = recs + (size_t)b * CAP;
    for (int i = threadIdx.x; i < cnt; i += 256) {
        uint2 rec = r[i];
        int src = rec.x & 0x1FFFF;
        int dl  = rec.x >> 17;
        float w = __uint_as_float(rec.y);
        float4 xv = reinterpret_cast<const float4*>(x)[src];
        atomicAdd(&acc[dl * 4 + 0], xv.x * w);
        atomicAdd(&acc[dl * 4 + 1], xv.y * w);
        atomicAdd(&acc[dl * 4 + 2], xv.z * w);
        atomicAdd(&acc[dl * 4 + 3], xv.w * w);
    }
    __syncthreads();

    for (int t = threadIdx.x; t < NB; t += 256) {
        float4 v = make_float4(acc[t * 4 + 0], acc[t * 4 + 1],
                               acc[t * 4 + 2], acc[t * 4 + 3]);
        reinterpret_cast<float4*>(agg)[b * NB + t] = v;
    }
}

// ---------------------------------------------------------------------------
// Per-node fused MLP; h lives only in registers.
// ---------------------------------------------------------------------------
__global__ __launch_bounds__(256) void node_kernel(const float* __restrict__ x,
                            const float* __restrict__ agg,
                            const float* __restrict__ W1_rel,
                            const float* __restrict__ b1,
                            const float* __restrict__ W1_root,
                            const float* __restrict__ W2_rel,
                            const float* __restrict__ b2,
                            const float* __restrict__ W2_root,
                            float* __restrict__ s_rel,
                            float* __restrict__ out) {
    __shared__ float sW1r[4 * HIDDEN];
    __shared__ float sW1o[4 * HIDDEN];
    __shared__ float sb1[HIDDEN];
    __shared__ float sW2r[HIDDEN];
    __shared__ float sW2o[HIDDEN];

    for (int i = threadIdx.x; i < 4 * HIDDEN; i += blockDim.x) {
        sW1r[i] = W1_rel[i];
        sW1o[i] = W1_root[i];
    }
    for (int i = threadIdx.x; i < HIDDEN; i += blockDim.x) {
        sb1[i]  = b1[i];
        sW2r[i] = W2_rel[i];
        sW2o[i] = W2_root[i];
    }
    __syncthreads();

    int n = blockIdx.x * blockDim.x + threadIdx.x;
    if (n >= N_NODES) return;

    float4 xv = reinterpret_cast<const float4*>(x)[n];
    float4 av = reinterpret_cast<const float4*>(agg)[n];

    float srel = 0.f, sroot = 0.f;
#pragma unroll 4
    for (int j = 0; j < HIDDEN; ++j) {
        float pre = sb1[j]
                  + av.x * sW1r[0 * HIDDEN + j]
                  + av.y * sW1r[1 * HIDDEN + j]
                  + av.z * sW1r[2 * HIDDEN + j]
                  + av.w * sW1r[3 * HIDDEN + j]
                  + xv.x * sW1o[0 * HIDDEN + j]
                  + xv.y * sW1o[1 * HIDDEN + j]
                  + xv.z * sW1o[2 * HIDDEN + j]
                  + xv.w * sW1o[3 * HIDDEN + j];
        float h = fmaxf(pre, 0.f);
        srel  += h * sW2r[j];
        sroot += h * sW2o[j];
    }
    s_rel[n] = srel;
    out[n]   = sroot + b2[0];
}

// ---------------------------------------------------------------------------
// Layer-2 aggregation: scalar LDS accumulate, non-atomic out +=.
// ---------------------------------------------------------------------------
template <int CAP>
__global__ __launch_bounds__(256) void agg2_kernel(const uint2* __restrict__ recs,
                                                   const int* __restrict__ cursor,
                                                   const float* __restrict__ s_rel,
                                                   float* __restrict__ out) {
    __shared__ float acc[NB];
    for (int i = threadIdx.x; i < NB; i += 256) acc[i] = 0.f;
    __syncthreads();

    const int b = blockIdx.x;
    const int cnt = min(cursor[b], CAP);
    const uint2* r = recs + (size_t)b * CAP;
    for (int i = threadIdx.x; i < cnt; i += 256) {
        uint2 rec = r[i];
        int src = rec.x & 0x1FFFF;
        int dl  = rec.x >> 17;
        atomicAdd(&acc[dl], s_rel[src] * __uint_as_float(rec.y));
    }
    __syncthreads();

    for (int t = threadIdx.x; t < NB; t += 256)
        out[b * NB + t] += acc[t];
}

// ---------------------------------------------------------------------------
// Legacy fallback (ws too small): direct global-atomic path.
// ---------------------------------------------------------------------------
__global__ void scatter1_legacy(const int* __restrict__ ei, const float* __restrict__ ea,
                                const float* __restrict__ x, float* __restrict__ agg) {
    int e = blockIdx.x * blockDim.x + threadIdx.x;
    if (e >= N_EDGES) return;
    int src = ei[e], dst = ei[N_EDGES + e];
    float w = ea[e];
    float4 xv = reinterpret_cast<const float4*>(x)[src];
    atomicAdd(&agg[dst * 4 + 0], xv.x * w);
    atomicAdd(&agg[dst * 4 + 1], xv.y * w);
    atomicAdd(&agg[dst * 4 + 2], xv.z * w);
    atomicAdd(&agg[dst * 4 + 3], xv.w * w);
}

__global__ void scatter2_legacy(const int* __restrict__ ei, const float* __restrict__ ea,
                                const float* __restrict__ s_rel, float* __restrict__ out) {
    int e = blockIdx.x * blockDim.x + threadIdx.x;
    if (e >= N_EDGES) return;
    atomicAdd(&out[ei[N_EDGES + e]], s_rel[ei[e]] * ea[e]);
}

extern "C" void kernel_launch(void* const* d_in, const int* in_sizes, int n_in,
                              void* d_out, int out_size, void* d_ws, size_t ws_size,
                              hipStream_t stream) {
    const float* x       = (const float*)d_in[0];
    const int*   ei      = (const int*)  d_in[1];
    const float* ea      = (const float*)d_in[2];
    const float* W1_rel  = (const float*)d_in[3];
    const float* b1      = (const float*)d_in[4];
    const float* W1_root = (const float*)d_in[5];
    const float* W2_rel  = (const float*)d_in[6];
    const float* b2      = (const float*)d_in[7];
    const float* W2_root = (const float*)d_in[8];
    float* out = (float*)d_out;
    char*  ws  = (char*)d_ws;

    // ws layout: agg [N*4 f] | s_rel [N f] | cursor [512 ints] | recs [NBKT*CAP uint2]
    float* agg    = (float*)ws;
    float* s_rel  = agg + (size_t)N_NODES * 4;
    int*   cursor = (int*)(s_rel + N_NODES);
    uint2* recs   = (uint2*)((char*)cursor + 2048);
    const size_t head = (size_t)N_NODES * 4 * 4 + (size_t)N_NODES * 4 + 2048;

    dim3 blk(256);
    dim3 grdN((N_NODES + 255) / 256);

    auto run_bucketed = [&](auto cap_tag) {
        constexpr int CAP = decltype(cap_tag)::value;
        zero_cursor<<<1, PT, 0, stream>>>(cursor);
        partition_kernel<CAP><<<PB, PT, 0, stream>>>(ei, ea, recs, cursor);
        agg1_kernel<CAP><<<NBKT, blk, 0, stream>>>(recs, cursor, x, agg);
        node_kernel<<<grdN, blk, 0, stream>>>(x, agg, W1_rel, b1, W1_root,
                                              W2_rel, b2, W2_root, s_rel, out);
        agg2_kernel<CAP><<<NBKT, blk, 0, stream>>>(recs, cursor, s_rel, out);
    };

    if (ws_size >= head + (size_t)NBKT * 2048 * sizeof(uint2)) {
        run_bucketed(std::integral_constant<int, 2048>{});
    } else if (ws_size >= head + (size_t)NBKT * 1664 * sizeof(uint2)) {
        run_bucketed(std::integral_constant<int, 1664>{});
    } else {
        dim3 grdE((N_EDGES + 255) / 256);
        hipMemsetAsync(agg, 0, (size_t)N_NODES * 4 * sizeof(float), stream);
        scatter1_legacy<<<grdE, blk, 0, stream>>>(ei, ea, x, agg);
        node_kernel<<<grdN, blk, 0, stream>>>(x, agg, W1_rel, b1, W1_root,
                                              W2_rel, b2, W2_root, s_rel, out);
        scatter2_legacy<<<grdE, blk, 0, stream>>>(ei, ea, s_rel, out);
    }
}

// Round 5
// 55.006 us; speedup vs baseline: 3.5830x; 1.1718x over previous
//
#include <hip/hip_runtime.h>
#include <type_traits>

#define N_NODES 100000
#define N_EDGES 640000
#define HIDDEN 128

// Bucketed counting-sort parameters
#define NB   200              // nodes per bucket
#define NBKT 500              // buckets; NB*NBKT == N_NODES
#define PB   125              // partition blocks
#define PT   512              // partition threads
#define EPT  10               // edges/thread: PB*PT*EPT == N_EDGES
#define BLK_RECS (PT * EPT)   // 5120 records per partition block

// ---------------------------------------------------------------------------
// Prep: zero bucket cursors AND pack per-column weights contiguously:
//   packed[j*12 + 0..3] = W1_rel[0..3][j]
//   packed[j*12 + 4..7] = W1_root[0..3][j]
//   packed[j*12 + 8..10] = b1[j], W2_rel[j], W2_root[j]   (+ pad)
// so the fused MLP can read them as 3 wave-uniform float4 loads (SGPR path).
// ---------------------------------------------------------------------------
__global__ __launch_bounds__(PT) void prep_kernel(int* __restrict__ cursor,
                                                  const float* __restrict__ W1_rel,
                                                  const float* __restrict__ b1,
                                                  const float* __restrict__ W1_root,
                                                  const float* __restrict__ W2_rel,
                                                  const float* __restrict__ W2_root,
                                                  float* __restrict__ packed) {
    int t = threadIdx.x;
    if (t < NBKT) cursor[t] = 0;
    if (t < HIDDEN) {
        float* p = packed + t * 12;
#pragma unroll
        for (int k = 0; k < 4; ++k) p[k]     = W1_rel[k * HIDDEN + t];
#pragma unroll
        for (int k = 0; k < 4; ++k) p[4 + k] = W1_root[k * HIDDEN + t];
        p[8]  = b1[t];
        p[9]  = W2_rel[t];
        p[10] = W2_root[t];
        p[11] = 0.f;
    }
}

// ---------------------------------------------------------------------------
// Partition with LDS sort: bin edges by dst bucket, sort the block's 5120
// records by bucket in LDS, write bucket-contiguous coalesced runs.
// Record: x = src | (dst_local << 17), y = w bits.
// ---------------------------------------------------------------------------
template <int CAP>
__global__ __launch_bounds__(PT) void partition_kernel(const int* __restrict__ ei,
                                                       const float* __restrict__ ea,
                                                       uint2* __restrict__ recs,
                                                       int* __restrict__ cursor) {
    __shared__ int   hist[NBKT];
    __shared__ int   start[NBKT + 1];
    __shared__ int   wcur[NBKT];
    __shared__ int   gbase[NBKT];
    __shared__ int   scan[PT];
    __shared__ uint2 srec[BLK_RECS];   // 40 KB

    const int tid = threadIdx.x;

    for (int i = tid; i < NBKT; i += PT) hist[i] = 0;
    __syncthreads();

    const int e0 = blockIdx.x * BLK_RECS + tid;
    int   dsts[EPT];
    int   srcs[EPT];
    float wts[EPT];
#pragma unroll
    for (int k = 0; k < EPT; ++k) {
        int e = e0 + k * PT;
        srcs[k] = ei[e];
        dsts[k] = ei[N_EDGES + e];
        wts[k]  = ea[e];
        atomicAdd(&hist[dsts[k] / NB], 1);
    }
    __syncthreads();

    // Exclusive scan (Hillis-Steele over PT slots).
    int v = (tid < NBKT) ? hist[tid] : 0;
    scan[tid] = v;
    __syncthreads();
#pragma unroll
    for (int off = 1; off < PT; off <<= 1) {
        int t = (tid >= off) ? scan[tid - off] : 0;
        __syncthreads();
        scan[tid] += t;
        __syncthreads();
    }
    if (tid < NBKT) {
        start[tid] = scan[tid] - v;
        wcur[tid]  = scan[tid] - v;
        gbase[tid] = v ? atomicAdd(&cursor[tid], v) : 0;
    }
    if (tid == 0) start[NBKT] = BLK_RECS;
    __syncthreads();

    // Scatter records into LDS in bucket-sorted order.
#pragma unroll
    for (int k = 0; k < EPT; ++k) {
        int d  = dsts[k];
        int b  = d / NB;
        int dl = d - b * NB;
        int slot = atomicAdd(&wcur[b], 1);
        srec[slot] = make_uint2((unsigned)srcs[k] | ((unsigned)dl << 17),
                                __float_as_uint(wts[k]));
    }
    __syncthreads();

    // Stream sorted records out; bucket via binary search on start[].
    for (int j = tid; j < BLK_RECS; j += PT) {
        int lo = 0, hi = NBKT;
        while (hi - lo > 1) {
            int mid = (lo + hi) >> 1;
            if (start[mid] <= j) lo = mid; else hi = mid;
        }
        int off = gbase[lo] + (j - start[lo]);
        if (off < CAP)
            recs[(size_t)lo * CAP + off] = srec[j];
    }
}

// ---------------------------------------------------------------------------
// FUSED layer-1 aggregation + per-node MLP.
// Block b owns nodes [b*NB, (b+1)*NB): accumulate messages into LDS, then
// compute h/relu/s_rel/out for those nodes in-register. Weights arrive as
// wave-uniform packed float4 loads (scalar path, no LDS traffic).
// ---------------------------------------------------------------------------
template <int CAP>
__global__ __launch_bounds__(256) void fused_kernel(const uint2* __restrict__ recs,
                                                    const int* __restrict__ cursor,
                                                    const float* __restrict__ x,
                                                    const float* __restrict__ packed,
                                                    const float* __restrict__ b2,
                                                    float* __restrict__ s_rel,
                                                    float* __restrict__ out) {
    __shared__ float acc[NB * 4];
    for (int i = threadIdx.x; i < NB * 4; i += 256) acc[i] = 0.f;
    __syncthreads();

    const int b = blockIdx.x;
    const int cnt = min(cursor[b], CAP);
    const uint2* r = recs + (size_t)b * CAP;
    for (int i = threadIdx.x; i < cnt; i += 256) {
        uint2 rec = r[i];
        int src = rec.x & 0x1FFFF;
        int dl  = rec.x >> 17;
        float w = __uint_as_float(rec.y);
        float4 xv = reinterpret_cast<const float4*>(x)[src];
        atomicAdd(&acc[dl * 4 + 0], xv.x * w);
        atomicAdd(&acc[dl * 4 + 1], xv.y * w);
        atomicAdd(&acc[dl * 4 + 2], xv.z * w);
        atomicAdd(&acc[dl * 4 + 3], xv.w * w);
    }
    __syncthreads();

    const int t = threadIdx.x;
    if (t >= NB) return;
    const int n = b * NB + t;

    float4 xv = reinterpret_cast<const float4*>(x)[n];
    float4 av = make_float4(acc[t * 4 + 0], acc[t * 4 + 1],
                            acc[t * 4 + 2], acc[t * 4 + 3]);

    const float4* pw = reinterpret_cast<const float4*>(packed);
    float srel = 0.f, sroot = 0.f;
#pragma unroll 4
    for (int j = 0; j < HIDDEN; ++j) {
        float4 wr = pw[j * 3 + 0];   // W1_rel[0..3][j]
        float4 wo = pw[j * 3 + 1];   // W1_root[0..3][j]
        float4 wb = pw[j * 3 + 2];   // b1, W2_rel, W2_root, pad
        float pre = wb.x
                  + av.x * wr.x + av.y * wr.y + av.z * wr.z + av.w * wr.w
                  + xv.x * wo.x + xv.y * wo.y + xv.z * wo.z + xv.w * wo.w;
        float h = fmaxf(pre, 0.f);
        srel  += h * wb.y;
        sroot += h * wb.z;
    }
    s_rel[n] = srel;
    out[n]   = sroot + b2[0];
}

// ---------------------------------------------------------------------------
// Layer-2 aggregation: scalar LDS accumulate, non-atomic out +=.
// ---------------------------------------------------------------------------
template <int CAP>
__global__ __launch_bounds__(256) void agg2_kernel(const uint2* __restrict__ recs,
                                                   const int* __restrict__ cursor,
                                                   const float* __restrict__ s_rel,
                                                   float* __restrict__ out) {
    __shared__ float acc[NB];
    for (int i = threadIdx.x; i < NB; i += 256) acc[i] = 0.f;
    __syncthreads();

    const int b = blockIdx.x;
    const int cnt = min(cursor[b], CAP);
    const uint2* r = recs + (size_t)b * CAP;
    for (int i = threadIdx.x; i < cnt; i += 256) {
        uint2 rec = r[i];
        int src = rec.x & 0x1FFFF;
        int dl  = rec.x >> 17;
        atomicAdd(&acc[dl], s_rel[src] * __uint_as_float(rec.y));
    }
    __syncthreads();

    for (int t = threadIdx.x; t < NB; t += 256)
        out[b * NB + t] += acc[t];
}

// ---------------------------------------------------------------------------
// Legacy fallback (ws too small): direct global-atomic path.
// ---------------------------------------------------------------------------
__global__ void scatter1_legacy(const int* __restrict__ ei, const float* __restrict__ ea,
                                const float* __restrict__ x, float* __restrict__ agg) {
    int e = blockIdx.x * blockDim.x + threadIdx.x;
    if (e >= N_EDGES) return;
    int src = ei[e], dst = ei[N_EDGES + e];
    float w = ea[e];
    float4 xv = reinterpret_cast<const float4*>(x)[src];
    atomicAdd(&agg[dst * 4 + 0], xv.x * w);
    atomicAdd(&agg[dst * 4 + 1], xv.y * w);
    atomicAdd(&agg[dst * 4 + 2], xv.z * w);
    atomicAdd(&agg[dst * 4 + 3], xv.w * w);
}

__global__ __launch_bounds__(256) void node_legacy(const float* __restrict__ x,
                            const float* __restrict__ agg,
                            const float* __restrict__ packed,
                            const float* __restrict__ b2,
                            float* __restrict__ s_rel,
                            float* __restrict__ out) {
    int n = blockIdx.x * blockDim.x + threadIdx.x;
    if (n >= N_NODES) return;
    float4 xv = reinterpret_cast<const float4*>(x)[n];
    float4 av = reinterpret_cast<const float4*>(agg)[n];
    const float4* pw = reinterpret_cast<const float4*>(packed);
    float srel = 0.f, sroot = 0.f;
#pragma unroll 4
    for (int j = 0; j < HIDDEN; ++j) {
        float4 wr = pw[j * 3 + 0];
        float4 wo = pw[j * 3 + 1];
        float4 wb = pw[j * 3 + 2];
        float pre = wb.x
                  + av.x * wr.x + av.y * wr.y + av.z * wr.z + av.w * wr.w
                  + xv.x * wo.x + xv.y * wo.y + xv.z * wo.z + xv.w * wo.w;
        float h = fmaxf(pre, 0.f);
        srel  += h * wb.y;
        sroot += h * wb.z;
    }
    s_rel[n] = srel;
    out[n]   = sroot + b2[0];
}

__global__ void scatter2_legacy(const int* __restrict__ ei, const float* __restrict__ ea,
                                const float* __restrict__ s_rel, float* __restrict__ out) {
    int e = blockIdx.x * blockDim.x + threadIdx.x;
    if (e >= N_EDGES) return;
    atomicAdd(&out[ei[N_EDGES + e]], s_rel[ei[e]] * ea[e]);
}

extern "C" void kernel_launch(void* const* d_in, const int* in_sizes, int n_in,
                              void* d_out, int out_size, void* d_ws, size_t ws_size,
                              hipStream_t stream) {
    const float* x       = (const float*)d_in[0];
    const int*   ei      = (const int*)  d_in[1];
    const float* ea      = (const float*)d_in[2];
    const float* W1_rel  = (const float*)d_in[3];
    const float* b1      = (const float*)d_in[4];
    const float* W1_root = (const float*)d_in[5];
    const float* W2_rel  = (const float*)d_in[6];
    const float* b2      = (const float*)d_in[7];
    const float* W2_root = (const float*)d_in[8];
    float* out = (float*)d_out;
    char*  ws  = (char*)d_ws;

    // ws layout: packed [1536 f] | s_rel [N f] | cursor [512 i] | recs [NBKT*CAP u2]
    float* packed = (float*)ws;
    float* s_rel  = packed + 1536;
    int*   cursor = (int*)(s_rel + N_NODES);
    uint2* recs   = (uint2*)((char*)cursor + 2048);
    const size_t head = 1536 * 4 + (size_t)N_NODES * 4 + 2048;

    dim3 grdN((N_NODES + 255) / 256);

    auto run_bucketed = [&](auto cap_tag) {
        constexpr int CAP = decltype(cap_tag)::value;
        prep_kernel<<<1, PT, 0, stream>>>(cursor, W1_rel, b1, W1_root,
                                          W2_rel, W2_root, packed);
        partition_kernel<CAP><<<PB, PT, 0, stream>>>(ei, ea, recs, cursor);
        fused_kernel<CAP><<<NBKT, 256, 0, stream>>>(recs, cursor, x, packed,
                                                    b2, s_rel, out);
        agg2_kernel<CAP><<<NBKT, 256, 0, stream>>>(recs, cursor, s_rel, out);
    };

    if (ws_size >= head + (size_t)NBKT * 2048 * sizeof(uint2)) {
        run_bucketed(std::integral_constant<int, 2048>{});
    } else if (ws_size >= head + (size_t)NBKT * 1664 * sizeof(uint2)) {
        run_bucketed(std::integral_constant<int, 1664>{});
    } else {
        // Legacy global-atomic path; agg array lives where recs would.
        float* agg = (float*)recs;
        dim3 grdE((N_EDGES + 255) / 256);
        prep_kernel<<<1, PT, 0, stream>>>(cursor, W1_rel, b1, W1_root,
                                          W2_rel, W2_root, packed);
        hipMemsetAsync(agg, 0, (size_t)N_NODES * 4 * sizeof(float), stream);
        scatter1_legacy<<<grdE, 256, 0, stream>>>(ei, ea, x, agg);
        node_legacy<<<grdN, 256, 0, stream>>>(x, agg, packed, b2, s_rel, out);
        scatter2_legacy<<<grdE, 256, 0, stream>>>(ei, ea, s_rel, out);
    }
}